// Round 27
// baseline (5694.442 us; speedup 1.0000x reference)
//
#include <hip/hip_runtime.h>
#include <cmath>

#define NB   256
#define NT   64
#define DATA 256
#define DD   264
#define NSUB 4
#define NTH  1024
#define NW   16
#define PI_F 3.14159265358979323846f

typedef _Float16 h2 __attribute__((ext_vector_type(2)));
typedef __fp16   g2 __attribute__((ext_vector_type(2)));

// ---- d_ws u32 offsets: f16 pairs ALONG K ----
#define WS_W0  0                        // [136 kk][256 j]
#define WS_W1  (WS_W0 + 136 * 256)      // [128][256]
#define WS_W2  (WS_W1 + 128 * 256)      // [128][256]
#define WS_W3  (WS_W2 + 128 * 256)      // [128][256]
#define WS_W3T (WS_W3 + 128 * 256)      // [128][16] cols 256..271 (>=264 pad 0)

// ---- LDS word offsets (identical to R22) ----
#define L_W1   0                        // [128 kk][256 u32] = 128 KB
#define L_PS   (L_W1 + 128 * 256)       // fp32 [16][272]
#define L_YP   (L_PS + NW * 272)        // 136 u32 packed y pairs
#define L_INP  (L_YP + 136)             // 136 u32 packed s_in pairs
#define L_HAP  (L_INP + 136)            // 128 u32
#define L_HBP  (L_HAP + 128)            // 128 u32
#define L_Y    (L_HBP + 128)            // 272 fp32 state
#define L_ACC  (L_Y + 272)              // 272
#define L_B0   (L_ACC + 272)            // 256
#define L_B1   (L_B0 + 256)             // 256
#define L_B2   (L_B1 + 256)             // 256
#define L_B3   (L_B2 + 256)             // 272
#define LDS_WORDS (L_B3 + 272)          // 39232 words = 156,928 B -> 1 blk/CU

__device__ __forceinline__ float dot2(unsigned wu, unsigned hu, float c) {
  h2 a = __builtin_bit_cast(h2, wu);
  h2 b = __builtin_bit_cast(h2, hu);
#if __has_builtin(__builtin_amdgcn_fdot2)
  return __builtin_amdgcn_fdot2(a, b, c, false);
#else
  return c + (float)a[0] * (float)b[0] + (float)a[1] * (float)b[1];
#endif
}
__device__ __forceinline__ unsigned pkh(float a, float b) {
#if __has_builtin(__builtin_amdgcn_cvt_pkrtz)
  g2 v = __builtin_amdgcn_cvt_pkrtz(a, b);
  return __builtin_bit_cast(unsigned, v);
#else
  h2 v; v[0] = (_Float16)a; v[1] = (_Float16)b;
  return __builtin_bit_cast(unsigned, v);
#endif
}
__device__ __forceinline__ unsigned pkh_rne(float a, float b) {
  h2 v; v[0] = (_Float16)a; v[1] = (_Float16)b;
  return __builtin_bit_cast(unsigned, v);
}

#define DOT4(acc, u, hp)                                                      \
  acc.x = dot2(u.x, hp, acc.x);                                               \
  acc.y = dot2(u.y, hp, acc.y);                                               \
  acc.z = dot2(u.z, hp, acc.z);                                               \
  acc.w = dot2(u.w, hp, acc.w);

__global__ void prep(const float* __restrict__ W0, const float* __restrict__ W1,
                     const float* __restrict__ W2, const float* __restrict__ W3,
                     unsigned* __restrict__ wsu) {
  int tid = blockIdx.x * blockDim.x + threadIdx.x;
  int stride = gridDim.x * blockDim.x;
  for (int i = tid; i < 136 * 256; i += stride) {
    int kk = i >> 8, j = i & 255;
    int k0 = 2 * kk, k1 = 2 * kk + 1;
    float lo = (k0 < DD) ? W0[j * DD + k0] : 0.f;
    float hi = (k1 < DD) ? W0[j * DD + k1] : 0.f;
    wsu[WS_W0 + i] = pkh_rne(lo, hi);
  }
  for (int i = tid; i < 128 * 256; i += stride) {
    int kk = i >> 8, j = i & 255;
    wsu[WS_W1 + i] = pkh_rne(W1[j * 256 + 2 * kk], W1[j * 256 + 2 * kk + 1]);
    wsu[WS_W2 + i] = pkh_rne(W2[j * 256 + 2 * kk], W2[j * 256 + 2 * kk + 1]);
    wsu[WS_W3 + i] = pkh_rne(W3[j * 256 + 2 * kk], W3[j * 256 + 2 * kk + 1]);
  }
  for (int i = tid; i < 128 * 16; i += stride) {
    int kk = i >> 4, c = 256 + (i & 15);
    float lo = (c < DD) ? W3[c * 256 + 2 * kk] : 0.f;
    float hi = (c < DD) ? W3[c * 256 + 2 * kk + 1] : 0.f;
    wsu[WS_W3T + i] = pkh_rne(lo, hi);
  }
}

// R27 = R22 (best verified, 4.70ms) + cross-barrier weight prefetch: the
// first 4 uint4 loads of each next stream phase are issued at the end of the
// current stream phase into named regs (pfa..pfd) and ride in flight across
// the barrier+reduce (~300cy, covers L2 latency). Weights are read-only ->
// no hazard. +16 VGPR (~52 total, grant 64). If dur is unchanged, hipcc
// drains vmcnt at __syncthreads and this design is at its plateau.
__global__ __launch_bounds__(NTH) void node_integrate(
    const float* __restrict__ ts, const float* __restrict__ xs,
    const float* __restrict__ a_sample,
    const float* __restrict__ b0g, const float* __restrict__ b1g,
    const float* __restrict__ b2g, const float* __restrict__ b3g,
    const unsigned* __restrict__ wsu, float* __restrict__ out) {
  extern __shared__ float sm[];
  unsigned* smu = (unsigned*)sm;
  const int b   = blockIdx.x;
  const int tid = threadIdx.x;
  const int w   = tid >> 6;    // wave 0..15
  const int l   = tid & 63;    // lane

  for (int i = tid; i < 256; i += NTH) {
    sm[L_B0 + i] = b0g[i];
    sm[L_B1 + i] = b1g[i];
    sm[L_B2 + i] = b2g[i];
  }
  for (int i = tid; i < 272; i += NTH) sm[L_B3 + i] = (i < DD) ? b3g[i] : 0.f;
  {
    const uint4* src = (const uint4*)(wsu + WS_W1);
    uint4* dst = (uint4*)(smu + L_W1);
    for (int i = tid; i < 128 * 64; i += NTH) dst[i] = src[i];
  }
  {
    const float sc = a_sample[b] * expf(-0.1f * ts[0]);
    for (int i = tid; i < 272; i += NTH) {
      float v = 0.f;
      if (i < DATA) v = sc * sinf(PI_F * xs[(size_t)b * DATA + i]);
      sm[L_Y + i] = v;
    }
  }
  __syncthreads();
  if (tid < 136) {
    smu[L_YP + tid]  = pkh(sm[L_Y + 2 * tid], sm[L_Y + 2 * tid + 1]);
    smu[L_INP + tid] = 0u;
  }
  __syncthreads();

  if (tid < DATA) out[((size_t)b * NT) * DATA + tid] = sm[L_Y + tid];

  float4* ps4 = (float4*)(sm + L_PS);
  const uint4* w0b4 = (const uint4*)(wsu + WS_W0);
  const uint4* w2b4 = (const uint4*)(wsu + WS_W2);
  const uint4* w3b4 = (const uint4*)(wsu + WS_W3);
  const uint4* w3t4 = (const uint4*)(wsu + WS_W3T);
  const uint4* w1l4 = (const uint4*)(smu + L_W1);

  // ---- persistent prefetch registers; primed with W0 pairs i=0..3
  uint4 pfa = w0b4[(w)      * 64 + l];
  uint4 pfb = w0b4[(w + 16) * 64 + l];
  uint4 pfc = w0b4[(w + 32) * 64 + l];
  uint4 pfd = w0b4[(w + 48) * 64 + l];

#pragma unroll 1
  for (int t = 0; t < NT - 1; ++t) {
    const float dt = ts[t + 1] - ts[t];
    const float h  = dt * (1.0f / NSUB);
#pragma unroll 1
    for (int sub = 0; sub < NSUB; ++sub) {
#pragma unroll 1
      for (int st = 0; st < 3; ++st) {
        const unsigned* finp = smu + ((st == 0) ? L_YP : L_INP);

        // ---- L0 stream: consume pf (i=0..3), load i=4..7 + tail
        {
          float4 acc; acc.x = acc.y = acc.z = acc.w = 0.f;
          DOT4(acc, pfa, finp[w])
          DOT4(acc, pfb, finp[w + 16])
          DOT4(acc, pfc, finp[w + 32])
          DOT4(acc, pfd, finp[w + 48])
#pragma unroll 4
          for (int i = 4; i < 8; ++i) {
            const int kk = w + 16 * i;
            const uint4 u = w0b4[kk * 64 + l];
            const unsigned hp = finp[kk];
            DOT4(acc, u, hp)
          }
          if (w < 8) {
            const int kk = 128 + w;
            const uint4 u = w0b4[kk * 64 + l];
            const unsigned hp = finp[kk];
            DOT4(acc, u, hp)
          }
          // prefetch W2 (consumed in L2 phase, 3 barriers later)
          pfa = w2b4[(w)      * 64 + l];
          pfb = w2b4[(w + 16) * 64 + l];
          pfc = w2b4[(w + 32) * 64 + l];
          pfd = w2b4[(w + 48) * 64 + l];
          ps4[w * 68 + l] = acc;
        }
        __syncthreads();
        if (tid < 256) {
          float sv = sm[L_B0 + tid];
#pragma unroll
          for (int ww = 0; ww < NW; ++ww) sv += sm[L_PS + ww * 272 + tid];
          const float hv = tanhf(sv);
          const float ho = __shfl_xor(hv, 1);
          if (!(tid & 1)) smu[L_HAP + (tid >> 1)] = pkh(hv, ho);
        }
        __syncthreads();

        // ---- L1 stream: all from LDS
        {
          float4 acc; acc.x = acc.y = acc.z = acc.w = 0.f;
#pragma unroll 4
          for (int i = 0; i < 8; ++i) {
            const int kk = w + 16 * i;
            const uint4 u = w1l4[kk * 64 + l];
            const unsigned hp = smu[L_HAP + kk];
            DOT4(acc, u, hp)
          }
          ps4[w * 68 + l] = acc;
        }
        __syncthreads();
        if (tid < 256) {
          float sv = sm[L_B1 + tid];
#pragma unroll
          for (int ww = 0; ww < NW; ++ww) sv += sm[L_PS + ww * 272 + tid];
          const float hv = tanhf(sv);
          const float ho = __shfl_xor(hv, 1);
          if (!(tid & 1)) smu[L_HBP + (tid >> 1)] = pkh(hv, ho);
        }
        __syncthreads();

        // ---- L2 stream: consume pf, load i=4..7
        {
          float4 acc; acc.x = acc.y = acc.z = acc.w = 0.f;
          DOT4(acc, pfa, smu[L_HBP + w])
          DOT4(acc, pfb, smu[L_HBP + w + 16])
          DOT4(acc, pfc, smu[L_HBP + w + 32])
          DOT4(acc, pfd, smu[L_HBP + w + 48])
#pragma unroll 4
          for (int i = 4; i < 8; ++i) {
            const int kk = w + 16 * i;
            const uint4 u = w2b4[kk * 64 + l];
            const unsigned hp = smu[L_HBP + kk];
            DOT4(acc, u, hp)
          }
          // prefetch W3
          pfa = w3b4[(w)      * 64 + l];
          pfb = w3b4[(w + 16) * 64 + l];
          pfc = w3b4[(w + 32) * 64 + l];
          pfd = w3b4[(w + 48) * 64 + l];
          ps4[w * 68 + l] = acc;
        }
        __syncthreads();
        if (tid < 256) {
          float sv = sm[L_B2 + tid];
#pragma unroll
          for (int ww = 0; ww < NW; ++ww) sv += sm[L_PS + ww * 272 + tid];
          const float hv = tanhf(sv);
          const float ho = __shfl_xor(hv, 1);
          if (!(tid & 1)) smu[L_HAP + (tid >> 1)] = pkh(hv, ho);
        }
        __syncthreads();

        // ---- L3 stream: consume pf, load i=4..7 + 16-col tail
        {
          float4 acc; acc.x = acc.y = acc.z = acc.w = 0.f;
          DOT4(acc, pfa, smu[L_HAP + w])
          DOT4(acc, pfb, smu[L_HAP + w + 16])
          DOT4(acc, pfc, smu[L_HAP + w + 32])
          DOT4(acc, pfd, smu[L_HAP + w + 48])
#pragma unroll 4
          for (int i = 4; i < 8; ++i) {
            const int kk = w + 16 * i;
            const uint4 u = w3b4[kk * 64 + l];
            const unsigned hp = smu[L_HAP + kk];
            DOT4(acc, u, hp)
          }
          ps4[w * 68 + l] = acc;
          if (l < 4) {
            float4 accx; accx.x = accx.y = accx.z = accx.w = 0.f;
#pragma unroll 4
            for (int i = 0; i < 8; ++i) {
              const int kk = w + 16 * i;
              const uint4 u = w3t4[kk * 4 + l];
              const unsigned hp = smu[L_HAP + kk];
              DOT4(accx, u, hp)
            }
            ps4[w * 68 + 64 + l] = accx;
          }
          // prefetch W0 for the next eval
          pfa = w0b4[(w)      * 64 + l];
          pfb = w0b4[(w + 16) * 64 + l];
          pfc = w0b4[(w + 32) * 64 + l];
          pfd = w0b4[(w + 48) * 64 + l];
        }
        __syncthreads();
        // ---- reduce + RK + repack fin ----
        if (tid < DD) {
          float kv = sm[L_B3 + tid];
#pragma unroll
          for (int ww = 0; ww < NW; ++ww) kv += sm[L_PS + ww * 272 + tid];
          float val;
          if (st == 0) {
            sm[L_ACC + tid] = (2.0f / 9.0f) * kv;
            val = sm[L_Y + tid] + 0.5f * h * kv;
          } else if (st == 1) {
            sm[L_ACC + tid] += (1.0f / 3.0f) * kv;
            val = sm[L_Y + tid] + 0.75f * h * kv;
          } else {
            val = sm[L_Y + tid] + h * (sm[L_ACC + tid] + (4.0f / 9.0f) * kv);
            sm[L_Y + tid] = val;
          }
          const float vo = __shfl_xor(val, 1);
          if (!(tid & 1)) {
            const int dst = (st == 2) ? L_YP : L_INP;
            smu[dst + (tid >> 1)] = pkh(val, vo);
          }
        }
        __syncthreads();
      }
    }
    if (tid < DATA) out[((size_t)b * NT + (t + 1)) * DATA + tid] = sm[L_Y + tid];
  }
}

extern "C" void kernel_launch(void* const* d_in, const int* in_sizes, int n_in,
                              void* d_out, int out_size, void* d_ws, size_t ws_size,
                              hipStream_t stream) {
  const float* ts = (const float*)d_in[0];
  const float* xs = (const float*)d_in[1];
  const float* a  = (const float*)d_in[2];
  const float* W0 = (const float*)d_in[3];
  const float* b0 = (const float*)d_in[4];
  const float* W1 = (const float*)d_in[5];
  const float* b1 = (const float*)d_in[6];
  const float* W2 = (const float*)d_in[7];
  const float* b2 = (const float*)d_in[8];
  const float* W3 = (const float*)d_in[9];
  const float* b3 = (const float*)d_in[10];
  unsigned* ws = (unsigned*)d_ws;
  float* out = (float*)d_out;

  const size_t lds_bytes = LDS_WORDS * sizeof(float);
  (void)hipFuncSetAttribute(reinterpret_cast<const void*>(node_integrate),
                            hipFuncAttributeMaxDynamicSharedMemorySize,
                            (int)lds_bytes);

  hipLaunchKernelGGL(prep, dim3(256), dim3(256), 0, stream, W0, W1, W2, W3, ws);
  hipLaunchKernelGGL(node_integrate, dim3(NB), dim3(NTH), lds_bytes, stream,
                     ts, xs, a, b0, b1, b2, b3, ws, out);
}

// Round 28
// 4693.964 us; speedup vs baseline: 1.2131x; 1.2131x over previous
//
#include <hip/hip_runtime.h>
#include <cmath>

#define NB   256
#define NT   64
#define DATA 256
#define DD   264
#define NSUB 4
#define NTH  1024
#define NW   16
#define PI_F 3.14159265358979323846f

typedef _Float16 h2 __attribute__((ext_vector_type(2)));
typedef __fp16   g2 __attribute__((ext_vector_type(2)));   // cvt_pkrtz return type

// ---- d_ws u32 offsets: f16 pairs ALONG K ----
// u32 at [kk][j] = { W[2kk][j], W[2kk+1][j] } as f16 (slot0 = 2kk).
#define WS_W0  0                        // [136 kk][256 j]  (K=272 padded)
#define WS_W1  (WS_W0 + 136 * 256)      // [128][256]
#define WS_W2  (WS_W1 + 128 * 256)      // [128][256]
#define WS_W3  (WS_W2 + 128 * 256)      // [128][256]  cols 0..255
#define WS_W3T (WS_W3 + 128 * 256)      // [128][16]   cols 256..271 (>=264 pad 0)

// ---- LDS word offsets ----
#define L_W1   0                        // [128 kk][256 u32] f16-pair W1 = 128 KB
#define L_PS   (L_W1 + 128 * 256)       // fp32 [16][272]
#define L_YP   (L_PS + NW * 272)        // 136 u32: packed y pairs
#define L_INP  (L_YP + 136)             // 136 u32: packed s_in pairs
#define L_HAP  (L_INP + 136)            // 128 u32: packed hA pairs
#define L_HBP  (L_HAP + 128)            // 128 u32: packed hB pairs
#define L_Y    (L_HBP + 128)            // 272 fp32 state (pads 0)
#define L_ACC  (L_Y + 272)              // 272
#define L_B0   (L_ACC + 272)            // 256
#define L_B1   (L_B0 + 256)             // 256
#define L_B2   (L_B1 + 256)             // 256
#define L_B3   (L_B2 + 256)             // 272
#define LDS_WORDS (L_B3 + 272)          // 39232 words = 156,928 B -> 1 block/CU

__device__ __forceinline__ float dot2(unsigned wu, unsigned hu, float c) {
  h2 a = __builtin_bit_cast(h2, wu);
  h2 b = __builtin_bit_cast(h2, hu);
#if __has_builtin(__builtin_amdgcn_fdot2)
  return __builtin_amdgcn_fdot2(a, b, c, false);
#else
  return c + (float)a[0] * (float)b[0] + (float)a[1] * (float)b[1];
#endif
}

__device__ __forceinline__ unsigned pkh(float a, float b) {
#if __has_builtin(__builtin_amdgcn_cvt_pkrtz)
  g2 v = __builtin_amdgcn_cvt_pkrtz(a, b);
  return __builtin_bit_cast(unsigned, v);
#else
  h2 v; v[0] = (_Float16)a; v[1] = (_Float16)b;
  return __builtin_bit_cast(unsigned, v);
#endif
}

__device__ __forceinline__ unsigned pkh_rne(float a, float b) {
  h2 v; v[0] = (_Float16)a; v[1] = (_Float16)b;   // RNE casts (prep only)
  return __builtin_bit_cast(unsigned, v);
}

// DOT4: one uint4 (4 cols x k-pair) against one packed act pair
#define DOT4(acc, u, hp)                                                      \
  acc.x = dot2(u.x, hp, acc.x);                                               \
  acc.y = dot2(u.y, hp, acc.y);                                               \
  acc.z = dot2(u.z, hp, acc.z);                                               \
  acc.w = dot2(u.w, hp, acc.w);

__global__ void prep(const float* __restrict__ W0, const float* __restrict__ W1,
                     const float* __restrict__ W2, const float* __restrict__ W3,
                     unsigned* __restrict__ wsu) {
  int tid = blockIdx.x * blockDim.x + threadIdx.x;
  int stride = gridDim.x * blockDim.x;
  // W0 [256 out][264 in]: wsu[kk*256 + j] = {W0[j][2kk], W0[j][2kk+1]}
  for (int i = tid; i < 136 * 256; i += stride) {
    int kk = i >> 8, j = i & 255;
    int k0 = 2 * kk, k1 = 2 * kk + 1;
    float lo = (k0 < DD) ? W0[j * DD + k0] : 0.f;
    float hi = (k1 < DD) ? W0[j * DD + k1] : 0.f;
    wsu[WS_W0 + i] = pkh_rne(lo, hi);
  }
  for (int i = tid; i < 128 * 256; i += stride) {   // W1, W2, W3 main
    int kk = i >> 8, j = i & 255;
    wsu[WS_W1 + i] = pkh_rne(W1[j * 256 + 2 * kk], W1[j * 256 + 2 * kk + 1]);
    wsu[WS_W2 + i] = pkh_rne(W2[j * 256 + 2 * kk], W2[j * 256 + 2 * kk + 1]);
    wsu[WS_W3 + i] = pkh_rne(W3[j * 256 + 2 * kk], W3[j * 256 + 2 * kk + 1]);
  }
  // W3 tail cols 256..271 (>=264 pad 0): [128][16]
  for (int i = tid; i < 128 * 16; i += stride) {
    int kk = i >> 4, c = 256 + (i & 15);
    float lo = (c < DD) ? W3[c * 256 + 2 * kk] : 0.f;
    float hi = (c < DD) ? W3[c * 256 + 2 * kk + 1] : 0.f;
    wsu[WS_W3T + i] = pkh_rne(lo, hi);
  }
}

// R28 = R22 restored verbatim (session best: 4.70ms, absmax 0.0156, VGPR 36,
// FETCH 2.3MB, WRITE 16MB). Eight structural experiments (R23-R27) all lost
// to this simple 8-barrier schedule: barrier-halving added VALU+shfl work;
// cross-barrier prefetch spilled at the 64-reg grant (R27: VGPR=64, WRITE
// 37MB, 5.69ms). v_dot2_f32_f16 data path, f16 k-pair weights, bounded
// unroll 4 (full unroll hoists loads -> spill -> L2 pollution).
__global__ __launch_bounds__(NTH) void node_integrate(
    const float* __restrict__ ts, const float* __restrict__ xs,
    const float* __restrict__ a_sample,
    const float* __restrict__ b0g, const float* __restrict__ b1g,
    const float* __restrict__ b2g, const float* __restrict__ b3g,
    const unsigned* __restrict__ wsu, float* __restrict__ out) {
  extern __shared__ float sm[];
  unsigned* smu = (unsigned*)sm;
  const int b   = blockIdx.x;
  const int tid = threadIdx.x;
  const int w   = tid >> 6;    // wave 0..15
  const int l   = tid & 63;    // lane

  // ---- one-time fills ----
  for (int i = tid; i < 256; i += NTH) {
    sm[L_B0 + i] = b0g[i];
    sm[L_B1 + i] = b1g[i];
    sm[L_B2 + i] = b2g[i];
  }
  for (int i = tid; i < 272; i += NTH) sm[L_B3 + i] = (i < DD) ? b3g[i] : 0.f;
  {
    const uint4* src = (const uint4*)(wsu + WS_W1);
    uint4* dst = (uint4*)(smu + L_W1);
    for (int i = tid; i < 128 * 64; i += NTH) dst[i] = src[i];
  }
  {
    const float sc = a_sample[b] * expf(-0.1f * ts[0]);
    for (int i = tid; i < 272; i += NTH) {
      float v = 0.f;
      if (i < DATA) v = sc * sinf(PI_F * xs[(size_t)b * DATA + i]);
      sm[L_Y + i] = v;
    }
  }
  __syncthreads();
  // pack y pairs; s_in packed = 0 init (incl. pads)
  if (tid < 136) {
    smu[L_YP + tid]  = pkh(sm[L_Y + 2 * tid], sm[L_Y + 2 * tid + 1]);
    smu[L_INP + tid] = 0u;
  }
  __syncthreads();

  if (tid < DATA) out[((size_t)b * NT) * DATA + tid] = sm[L_Y + tid];

  float4* ps4 = (float4*)(sm + L_PS);                 // [16] rows of 68 float4
  const uint4* w0b4 = (const uint4*)(wsu + WS_W0);    // [136][64] uint4
  const uint4* w2b4 = (const uint4*)(wsu + WS_W2);    // [128][64]
  const uint4* w3b4 = (const uint4*)(wsu + WS_W3);    // [128][64]
  const uint4* w3t4 = (const uint4*)(wsu + WS_W3T);   // [128][4]
  const uint4* w1l4 = (const uint4*)(smu + L_W1);     // LDS [128][64]

#pragma unroll 1
  for (int t = 0; t < NT - 1; ++t) {
    const float dt = ts[t + 1] - ts[t];
    const float h  = dt * (1.0f / NSUB);
#pragma unroll 1
    for (int sub = 0; sub < NSUB; ++sub) {
#pragma unroll 1
      for (int st = 0; st < 3; ++st) {
        const unsigned* finp = smu + ((st == 0) ? L_YP : L_INP);

        // ---- L0: hA = tanh(W0 @ fin + b0); K=272 -> 136 k-pairs
        {
          float4 acc; acc.x = acc.y = acc.z = acc.w = 0.f;
#pragma unroll 4
          for (int i = 0; i < 8; ++i) {
            const int kk = w + 16 * i;          // < 128
            const uint4 u = w0b4[kk * 64 + l];
            const unsigned hp = finp[kk];
            DOT4(acc, u, hp)
          }
          if (w < 8) {                          // kk = 128..135
            const int kk = 128 + w;
            const uint4 u = w0b4[kk * 64 + l];
            const unsigned hp = finp[kk];
            DOT4(acc, u, hp)
          }
          ps4[w * 68 + l] = acc;
        }
        __syncthreads();
        if (tid < 256) {
          float sv = sm[L_B0 + tid];
#pragma unroll
          for (int ww = 0; ww < NW; ++ww) sv += sm[L_PS + ww * 272 + tid];
          const float hv = tanhf(sv);
          const float ho = __shfl_xor(hv, 1);
          if (!(tid & 1)) smu[L_HAP + (tid >> 1)] = pkh(hv, ho);
        }
        __syncthreads();

        // ---- L1: hB = tanh(W1 @ hA + b1); all from LDS
        {
          float4 acc; acc.x = acc.y = acc.z = acc.w = 0.f;
#pragma unroll 4
          for (int i = 0; i < 8; ++i) {
            const int kk = w + 16 * i;          // < 128
            const uint4 u = w1l4[kk * 64 + l];
            const unsigned hp = smu[L_HAP + kk];
            DOT4(acc, u, hp)
          }
          ps4[w * 68 + l] = acc;
        }
        __syncthreads();
        if (tid < 256) {
          float sv = sm[L_B1 + tid];
#pragma unroll
          for (int ww = 0; ww < NW; ++ww) sv += sm[L_PS + ww * 272 + tid];
          const float hv = tanhf(sv);
          const float ho = __shfl_xor(hv, 1);
          if (!(tid & 1)) smu[L_HBP + (tid >> 1)] = pkh(hv, ho);
        }
        __syncthreads();

        // ---- L2: hA = tanh(W2 @ hB + b2); streamed
        {
          float4 acc; acc.x = acc.y = acc.z = acc.w = 0.f;
#pragma unroll 4
          for (int i = 0; i < 8; ++i) {
            const int kk = w + 16 * i;
            const uint4 u = w2b4[kk * 64 + l];
            const unsigned hp = smu[L_HBP + kk];
            DOT4(acc, u, hp)
          }
          ps4[w * 68 + l] = acc;
        }
        __syncthreads();
        if (tid < 256) {
          float sv = sm[L_B2 + tid];
#pragma unroll
          for (int ww = 0; ww < NW; ++ww) sv += sm[L_PS + ww * 272 + tid];
          const float hv = tanhf(sv);
          const float ho = __shfl_xor(hv, 1);
          if (!(tid & 1)) smu[L_HAP + (tid >> 1)] = pkh(hv, ho);
        }
        __syncthreads();

        // ---- L3: kv = W3 @ hA + b3; main cols + 16-col tail
        {
          float4 acc; acc.x = acc.y = acc.z = acc.w = 0.f;
#pragma unroll 4
          for (int i = 0; i < 8; ++i) {
            const int kk = w + 16 * i;
            const uint4 u = w3b4[kk * 64 + l];
            const unsigned hp = smu[L_HAP + kk];
            DOT4(acc, u, hp)
          }
          ps4[w * 68 + l] = acc;
          if (l < 4) {
            float4 accx; accx.x = accx.y = accx.z = accx.w = 0.f;
#pragma unroll 4
            for (int i = 0; i < 8; ++i) {
              const int kk = w + 16 * i;
              const uint4 u = w3t4[kk * 4 + l];
              const unsigned hp = smu[L_HAP + kk];
              DOT4(accx, u, hp)
            }
            ps4[w * 68 + 64 + l] = accx;
          }
        }
        __syncthreads();
        // ---- reduce + RK + repack fin ----
        if (tid < DD) {
          float kv = sm[L_B3 + tid];
#pragma unroll
          for (int ww = 0; ww < NW; ++ww) kv += sm[L_PS + ww * 272 + tid];
          float val;
          if (st == 0) {
            sm[L_ACC + tid] = (2.0f / 9.0f) * kv;
            val = sm[L_Y + tid] + 0.5f * h * kv;
          } else if (st == 1) {
            sm[L_ACC + tid] += (1.0f / 3.0f) * kv;
            val = sm[L_Y + tid] + 0.75f * h * kv;
          } else {
            val = sm[L_Y + tid] + h * (sm[L_ACC + tid] + (4.0f / 9.0f) * kv);
            sm[L_Y + tid] = val;
          }
          const float vo = __shfl_xor(val, 1);
          if (!(tid & 1)) {
            const int dst = (st == 2) ? L_YP : L_INP;
            smu[dst + (tid >> 1)] = pkh(val, vo);
          }
        }
        __syncthreads();
      }
    }
    if (tid < DATA) out[((size_t)b * NT + (t + 1)) * DATA + tid] = sm[L_Y + tid];
  }
}

extern "C" void kernel_launch(void* const* d_in, const int* in_sizes, int n_in,
                              void* d_out, int out_size, void* d_ws, size_t ws_size,
                              hipStream_t stream) {
  const float* ts = (const float*)d_in[0];
  const float* xs = (const float*)d_in[1];
  const float* a  = (const float*)d_in[2];
  const float* W0 = (const float*)d_in[3];
  const float* b0 = (const float*)d_in[4];
  const float* W1 = (const float*)d_in[5];
  const float* b1 = (const float*)d_in[6];
  const float* W2 = (const float*)d_in[7];
  const float* b2 = (const float*)d_in[8];
  const float* W3 = (const float*)d_in[9];
  const float* b3 = (const float*)d_in[10];
  unsigned* ws = (unsigned*)d_ws;
  float* out = (float*)d_out;

  const size_t lds_bytes = LDS_WORDS * sizeof(float);
  (void)hipFuncSetAttribute(reinterpret_cast<const void*>(node_integrate),
                            hipFuncAttributeMaxDynamicSharedMemorySize,
                            (int)lds_bytes);

  hipLaunchKernelGGL(prep, dim3(256), dim3(256), 0, stream, W0, W1, W2, W3, ws);
  hipLaunchKernelGGL(node_integrate, dim3(NB), dim3(NTH), lds_bytes, stream,
                     ts, xs, a, b0, b1, b2, b3, ws, out);
}